// Round 4
// baseline (478.999 us; speedup 1.0000x reference)
//
#include <hip/hip_runtime.h>
#include <stdint.h>

#define EPS 1e-5f

typedef short bh8 __attribute__((ext_vector_type(8)));   // 8 bf16 in 4 VGPRs
typedef float f4v __attribute__((ext_vector_type(4)));   // MFMA accumulator
typedef unsigned short ushort_t;

static __device__ __forceinline__ unsigned short f2bf(float f) {
    unsigned u = __builtin_bit_cast(unsigned, f);
    u += 0x7fffu + ((u >> 16) & 1u);          // RNE
    return (unsigned short)(u >> 16);
}

static __device__ __forceinline__ float bfbits(unsigned x) {
    return __builtin_bit_cast(float, x);
}

// accumulate 16 channels (2×uint4 of bf16 pairs) into tv with mask m
static __device__ __forceinline__ void acc16(float* tv, uint4 qa, uint4 qb, float m) {
    unsigned w[8] = {qa.x, qa.y, qa.z, qa.w, qb.x, qb.y, qb.z, qb.w};
#pragma unroll
    for (int p = 0; p < 8; ++p) {
        tv[2 * p + 0] = fmaf(m, bfbits(w[p] << 16), tv[2 * p + 0]);
        tv[2 * p + 1] = fmaf(m, bfbits(w[p] & 0xffff0000u), tv[2 * p + 1]);
    }
}

// ---------------- ws layout (bytes) ----------------
// Pb   (bf16): 0          size 5,120,000
// WaT  (f32) : 5,120,000  size 40,960
// W1b  (bf16): 5,160,960  size 32,768
// Wfb  (bf16): 5,193,728  size 65,536
// cnt  (int) : 5,259,264  size 2,000,000
// cursor(int): 7,259,264  size 2,000,000
// rp   (int) : 9,259,264  size 2,000,004
// partials   : 11,259,392 size 492
// col  (int) : 11,261,440 size 2,000,000

__global__ void prep(const float* __restrict__ W1, const float* __restrict__ Wf,
                     const float* __restrict__ Wa, ushort_t* __restrict__ W1b,
                     ushort_t* __restrict__ Wfb, float* __restrict__ WaT) {
    int i = blockIdx.x * 256 + threadIdx.x;
    if (i < 16384) W1b[i] = f2bf(W1[i]);
    else if (i < 49152) { int j = i - 16384; Wfb[j] = f2bf(Wf[j]); }
    else if (i < 59392) { int l2 = i - 49152; int k = l2 >> 7, c = l2 & 127; WaT[l2] = Wa[c * 80 + k]; }
}

// ---------------- P = agt_x @ Wa^T  [A x 128] bf16 out, K=80 ----------------
__global__ __launch_bounds__(256) void proj_agents(const float* __restrict__ agt,
                                                   const float* __restrict__ WaT,
                                                   unsigned short* __restrict__ Pb) {
    __shared__ float WT[80 * 128];
    __shared__ float xT[80][32];
    int t = threadIdx.x;
    int row0 = blockIdx.x * 32;
#pragma unroll
    for (int m = 0; m < 40; ++m) WT[t + 256 * m] = WaT[t + 256 * m];
#pragma unroll
    for (int m = 0; m < 10; ++m) {
        int f = t + 256 * m;
        int r = f / 80, k = f - r * 80;
        xT[k][r] = agt[(size_t)(row0 + r) * 80 + k];
    }
    __syncthreads();
    int tx = t & 31, ty = t >> 5;
    float acc[4][4] = {};
    for (int k = 0; k < 80; ++k) {
        float4 xv = *(const float4*)&xT[k][ty * 4];
        float4 wv = *(const float4*)&WT[k * 128 + tx * 4];
        float xa[4] = {xv.x, xv.y, xv.z, xv.w};
        float wa[4] = {wv.x, wv.y, wv.z, wv.w};
#pragma unroll
        for (int i = 0; i < 4; ++i)
#pragma unroll
            for (int j = 0; j < 4; ++j) acc[i][j] = fmaf(xa[i], wa[j], acc[i][j]);
    }
#pragma unroll
    for (int i = 0; i < 4; ++i) {
        int r = row0 + ty * 4 + i;
        union { unsigned short s[4]; uint2 q; } o;
#pragma unroll
        for (int j = 0; j < 4; ++j) o.s[j] = f2bf(acc[i][j]);
        *(uint2*)&Pb[(size_t)r * 128 + tx * 4] = o.q;
    }
}

// ---------------- CSR build ----------------
__global__ void hist_v(const int* __restrict__ v, int* __restrict__ cnt, int E) {
    int e = blockIdx.x * 256 + threadIdx.x;
    if (e < E) atomicAdd(&cnt[v[e]], 1);
}

__global__ __launch_bounds__(256) void scan1(const int* __restrict__ cnt,
                                             int* __restrict__ rp,
                                             int* __restrict__ partials, int n) {
    __shared__ int lds[256];
    int b = blockIdx.x, t = threadIdx.x;
    int base = b * 4096 + t * 16;
    int vv[16];
    int run = 0;
#pragma unroll
    for (int i = 0; i < 16; ++i) {
        int c = (base + i < n) ? cnt[base + i] : 0;
        vv[i] = run;
        run += c;
    }
    lds[t] = run;
    __syncthreads();
#pragma unroll
    for (int off = 1; off < 256; off <<= 1) {
        int x = (t >= off) ? lds[t - off] : 0;
        __syncthreads();
        lds[t] += x;
        __syncthreads();
    }
    int excl = lds[t] - run;
    if (t == 255) partials[b] = lds[255];
#pragma unroll
    for (int i = 0; i < 16; ++i)
        if (base + i < n) rp[base + i] = excl + vv[i];
}

__global__ __launch_bounds__(256) void scan2(int* __restrict__ partials, int nb) {
    __shared__ int lds[256];
    int t = threadIdx.x;
    int vv = (t < nb) ? partials[t] : 0;
    lds[t] = vv;
    __syncthreads();
#pragma unroll
    for (int off = 1; off < 256; off <<= 1) {
        int x = (t >= off) ? lds[t - off] : 0;
        __syncthreads();
        lds[t] += x;
        __syncthreads();
    }
    if (t < nb) partials[t] = lds[t] - vv;
}

__global__ void scan3(int* __restrict__ rp, const int* __restrict__ partials,
                      int n, int E) {
    int i = blockIdx.x * 256 + threadIdx.x;
    if (i < n) rp[i] += partials[i >> 12];
    if (i == 0) rp[n] = E;
}

__global__ void fill_csr(const int* __restrict__ u, const int* __restrict__ v,
                         const int* __restrict__ rp, int* __restrict__ cursor,
                         int* __restrict__ col, int E) {
    int e = blockIdx.x * 256 + threadIdx.x;
    if (e < E) {
        int vv = v[e];
        int pos = rp[vv] + atomicAdd(&cursor[vv], 1);
        col[pos] = u[e];
    }
}

// ---------------- fused kernel ----------------
// 32 rows/tile, 4 waves; wave w owns output cols [32w,32w+32).
// Gather is software-pipelined one tile ahead: rp loads issued in GEMM2 phase,
// col loads issued post-bar2, Pb loads issued branchless (3 edges) at tile start.
__global__ __launch_bounds__(256, 3) void fused(
    const float* __restrict__ mapx, const float* __restrict__ W0,
    const float* __restrict__ b0, const ushort_t* __restrict__ W1b,
    const float* __restrict__ g1, const float* __restrict__ b1,
    const unsigned short* __restrict__ Pb, const int* __restrict__ rp,
    const int* __restrict__ col, const float* __restrict__ g_bn,
    const float* __restrict__ b_bn, const ushort_t* __restrict__ Wfb,
    const float* __restrict__ g_fc, const float* __restrict__ b_fc,
    float* __restrict__ out, int ntiles)
{
    __shared__ __align__(16) short h0s[32 * 128];    // 8 KB, XOR-swizzled (^=(row&7)<<4)
    __shared__ __align__(16) short cats[32 * 256];   // 16 KB, XOR-swizzled
    __shared__ float W0s[128 * 8];
    __shared__ float b0s[128];
    __shared__ float2 part[4][32];
    __shared__ float gA[128], bA[128], gB[128], bB[128], gC[128], bC[128];

    const int t = threadIdx.x;
    const int w = t >> 6;
    const int l = t & 63;
    const int l15 = l & 15, lg = l >> 4;
    const int r2 = t >> 3, c0 = (t & 7) * 16;        // gather: 8 threads/row, 16 ch

    if (t < 128) {
        gA[t] = g1[t];   bA[t] = b1[t];
        gB[t] = g_bn[t]; bB[t] = b_bn[t];
        gC[t] = g_fc[t]; bC[t] = b_fc[t];
        b0s[t] = b0[t];
    }
    for (int i = t; i < 1024; i += 256) W0s[i] = W0[i];

    // weight fragments (bf16, pre-converted) in registers
    bh8 w1b[2][4], wfb[2][8];
#pragma unroll
    for (int n = 0; n < 2; ++n) {
        const int wr = 32 * w + 16 * n + l15;        // weight row = output col
#pragma unroll
        for (int s = 0; s < 4; ++s)
            w1b[n][s] = *(const bh8*)(W1b + (size_t)wr * 128 + s * 32 + lg * 8);
#pragma unroll
        for (int s = 0; s < 8; ++s)
            wfb[n][s] = *(const bh8*)(Wfb + (size_t)wr * 256 + s * 32 + lg * 8);
    }
    __syncthreads();

    const f4v fzero = {0.f, 0.f, 0.f, 0.f};
    const int stride = (int)gridDim.x;

    // ---- prologue: prefetch gather indices for first tile ----
    int beg, deg, col0, col1, col2;
    {
        const int row = blockIdx.x * 32 + r2;
        beg = rp[row];
        deg = rp[row + 1] - beg;
        col0 = col[(deg > 0) ? beg : 0];
        col1 = col[(deg > 1) ? beg + 1 : 0];
        col2 = col[(deg > 2) ? beg + 2 : 0];
    }

    for (int tile = blockIdx.x; tile < ntiles; tile += stride) {
        const int row0 = tile * 32;
        const int tileN = tile + stride;
        const bool hasN = tileN < ntiles;

        // ===== phase A: issue all independent loads, h0 compute, tv accumulate =====
        const int rA = t & 31, cg = t >> 5;
        float mxv[8];
        {
            const float* p = mapx + (size_t)(row0 + rA) * 8;
            *(float4*)&mxv[0] = *(const float4*)p;
            *(float4*)&mxv[4] = *(const float4*)(p + 4);
        }
        const unsigned short* pB = Pb + c0;
        uint4 e0a = *(const uint4*)(pB + (size_t)col0 * 128);
        uint4 e0b = *(const uint4*)(pB + (size_t)col0 * 128 + 8);
        uint4 e1a = *(const uint4*)(pB + (size_t)col1 * 128);
        uint4 e1b = *(const uint4*)(pB + (size_t)col1 * 128 + 8);
        uint4 e2a = *(const uint4*)(pB + (size_t)col2 * 128);
        uint4 e2b = *(const uint4*)(pB + (size_t)col2 * 128 + 8);

        // h0 = relu(mapx@W0^T+b0) -> bf16 swizzled LDS (covers Pb load latency)
        {
            __align__(16) unsigned short hb[16];
#pragma unroll
            for (int c = 0; c < 16; ++c) {
                const int cc = 16 * cg + c;
                float a = b0s[cc];
#pragma unroll
                for (int j = 0; j < 8; ++j) a = fmaf(mxv[j], W0s[cc * 8 + j], a);
                hb[c] = f2bf(fmaxf(a, 0.f));
            }
            const int base = rA * 256 + cg * 32;
#pragma unroll
            for (int pc = 0; pc < 2; ++pc) {
                const int a = (base + 16 * pc) ^ ((rA & 7) << 4);
                *(uint4*)((char*)h0s + a) = *(const uint4*)&hb[8 * pc];
            }
        }

        // accumulate messages (branchless 3 edges + rare fallback)
        float tv[16] = {};
        acc16(tv, e0a, e0b, (deg > 0) ? 1.f : 0.f);
        acc16(tv, e1a, e1b, (deg > 1) ? 1.f : 0.f);
        acc16(tv, e2a, e2b, (deg > 2) ? 1.f : 0.f);
        for (int k = 3; k < deg; ++k) {
            const int a = col[beg + k];
            const unsigned short* pr = Pb + (size_t)a * 128 + c0;
            uint4 q0 = *(const uint4*)pr;
            uint4 q1 = *(const uint4*)(pr + 8);
            acc16(tv, q0, q1, 1.f);
        }
        __syncthreads();                              // (1) h0s ready

        // ===== GEMM2: h1 = h0 @ W1^T (K=128); prefetch rp for next tile =====
        int rpNlo = 0, rpNhi = 0;
        if (hasN) {
            const int rowN = tileN * 32 + r2;
            rpNlo = rp[rowN];
            rpNhi = rp[rowN + 1];
        }
        f4v acc2[2][2];
#pragma unroll
        for (int m = 0; m < 2; ++m)
#pragma unroll
            for (int n = 0; n < 2; ++n) acc2[m][n] = fzero;
#pragma unroll
        for (int s = 0; s < 4; ++s) {
            bh8 af[2];
#pragma unroll
            for (int m = 0; m < 2; ++m) {
                const int row = 16 * m + l15;
                const int a = (row * 256 + s * 64 + lg * 16) ^ ((row & 7) << 4);
                af[m] = *(const bh8*)((const char*)h0s + a);
            }
#pragma unroll
            for (int m = 0; m < 2; ++m)
#pragma unroll
                for (int n = 0; n < 2; ++n)
                    acc2[m][n] = __builtin_amdgcn_mfma_f32_16x16x32_bf16(
                        w1b[n][s], af[m], acc2[m][n], 0, 0, 0);
        }

        // GN1 partials: row = 16m+l15; reduce across lg via shfl
#pragma unroll
        for (int m = 0; m < 2; ++m) {
            float a = 0.f, q = 0.f;
#pragma unroll
            for (int n = 0; n < 2; ++n)
#pragma unroll
                for (int reg = 0; reg < 4; ++reg) {
                    float x = acc2[m][n][reg];
                    a += x; q += x * x;
                }
            a += __shfl_xor(a, 16, 64); q += __shfl_xor(q, 16, 64);
            a += __shfl_xor(a, 32, 64); q += __shfl_xor(q, 32, 64);
            if (lg == 0) part[w][16 * m + l15] = make_float2(a, q);
        }
        __syncthreads();                              // (2) part ready (rpN arrived too)

        // per-thread GN1 stats for rows {l15, 16+l15}
        float meanA[2], invA[2];
#pragma unroll
        for (int m = 0; m < 2; ++m) {
            const int row = 16 * m + l15;
            float2 p0 = part[0][row], p1 = part[1][row];
            float2 p2 = part[2][row], p3 = part[3][row];
            float a = p0.x + p1.x + p2.x + p3.x;
            float q = p0.y + p1.y + p2.y + p3.y;
            float mean = a * (1.f / 128.f);
            float var = q * (1.f / 128.f) - mean * mean;
            meanA[m] = mean;
            invA[m] = rsqrtf(var + EPS);
        }

        // prefetch col indices for next tile (rpN guaranteed arrived by bar2 drain)
        const int begN = rpNlo;
        const int degN = hasN ? (rpNhi - rpNlo) : 0;
        const int colN0 = col[(degN > 0) ? begN : 0];
        const int colN1 = col[(degN > 1) ? begN + 1 : 0];
        const int colN2 = col[(degN > 2) ? begN + 2 : 0];

        // normalized h -> cats[:,0:128] (8B writes)
#pragma unroll
        for (int m = 0; m < 2; ++m) {
            const int row = 16 * m + l15;
#pragma unroll
            for (int n = 0; n < 2; ++n) {
                const int c00 = 32 * w + 16 * n + 4 * lg;
                union { unsigned short s[4]; uint2 q; } o;
#pragma unroll
                for (int reg = 0; reg < 4; ++reg) {
                    float v2 = (acc2[m][n][reg] - meanA[m]) * invA[m] * gA[c00 + reg] + bA[c00 + reg];
                    o.s[reg] = f2bf(fmaxf(v2, 0.f));
                }
                const int a = (row * 512 + c00 * 2) ^ ((row & 7) << 4);
                *(uint2*)((char*)cats + a) = o.q;
            }
        }

        // message GN -> cats[:,128:256]
        {
            float a = 0.f, q = 0.f;
#pragma unroll
            for (int i = 0; i < 16; ++i) { a += tv[i]; q += tv[i] * tv[i]; }
#pragma unroll
            for (int msk = 1; msk < 8; msk <<= 1) {
                a += __shfl_xor(a, msk, 64);
                q += __shfl_xor(q, msk, 64);
            }
            const float mean = a * (1.f / 128.f);
            const float var = q * (1.f / 128.f) - mean * mean;
            const float inv = rsqrtf(var + EPS);
            __align__(16) unsigned short tb[16];
#pragma unroll
            for (int i = 0; i < 16; ++i) {
                const int cc = c0 + i;
                tb[i] = f2bf(fmaxf((tv[i] - mean) * inv * gB[cc] + bB[cc], 0.f));
            }
            const int base = r2 * 512 + 256 + c0 * 2;
#pragma unroll
            for (int pc = 0; pc < 2; ++pc) {
                const int ad = (base + 16 * pc) ^ ((r2 & 7) << 4);
                *(uint4*)((char*)cats + ad) = *(const uint4*)&tb[8 * pc];
            }
        }
        __syncthreads();                              // (3) cats ready

        // ===== GEMM3: [h,msg_n] @ Wf^T (K=256) =====
        f4v acc3[2][2];
#pragma unroll
        for (int m = 0; m < 2; ++m)
#pragma unroll
            for (int n = 0; n < 2; ++n) acc3[m][n] = fzero;
#pragma unroll
        for (int s = 0; s < 8; ++s) {
            bh8 af[2];
#pragma unroll
            for (int m = 0; m < 2; ++m) {
                const int row = 16 * m + l15;
                const int a = (row * 512 + s * 64 + lg * 16) ^ ((row & 7) << 4);
                af[m] = *(const bh8*)((const char*)cats + a);
            }
#pragma unroll
            for (int m = 0; m < 2; ++m)
#pragma unroll
                for (int n = 0; n < 2; ++n)
                    acc3[m][n] = __builtin_amdgcn_mfma_f32_16x16x32_bf16(
                        wfb[n][s], af[m], acc3[m][n], 0, 0, 0);
        }

        // GN-fc partials
#pragma unroll
        for (int m = 0; m < 2; ++m) {
            float a = 0.f, q = 0.f;
#pragma unroll
            for (int n = 0; n < 2; ++n)
#pragma unroll
                for (int reg = 0; reg < 4; ++reg) {
                    float x = acc3[m][n][reg];
                    a += x; q += x * x;
                }
            a += __shfl_xor(a, 16, 64); q += __shfl_xor(q, 16, 64);
            a += __shfl_xor(a, 32, 64); q += __shfl_xor(q, 32, 64);
            if (lg == 0) part[w][16 * m + l15] = make_float2(a, q);
        }
        __syncthreads();                              // (4) part ready

        // epilogue: per-thread stats, GN+ReLU, float4 store
#pragma unroll
        for (int m = 0; m < 2; ++m) {
            const int row = 16 * m + l15;
            float2 p0 = part[0][row], p1 = part[1][row];
            float2 p2 = part[2][row], p3 = part[3][row];
            float a = p0.x + p1.x + p2.x + p3.x;
            float q = p0.y + p1.y + p2.y + p3.y;
            float mean = a * (1.f / 128.f);
            float var = q * (1.f / 128.f) - mean * mean;
            float inv = rsqrtf(var + EPS);
#pragma unroll
            for (int n = 0; n < 2; ++n) {
                const int c00 = 32 * w + 16 * n + 4 * lg;
                float4 o;
                o.x = fmaxf((acc3[m][n][0] - mean) * inv * gC[c00 + 0] + bC[c00 + 0], 0.f);
                o.y = fmaxf((acc3[m][n][1] - mean) * inv * gC[c00 + 1] + bC[c00 + 1], 0.f);
                o.z = fmaxf((acc3[m][n][2] - mean) * inv * gC[c00 + 2] + bC[c00 + 2], 0.f);
                o.w = fmaxf((acc3[m][n][3] - mean) * inv * gC[c00 + 3] + bC[c00 + 3], 0.f);
                *(float4*)&out[(size_t)(row0 + row) * 128 + c00] = o;
            }
        }

        // rotate prefetched gather state
        beg = begN; deg = degN;
        col0 = colN0; col1 = colN1; col2 = colN2;
    }
}

extern "C" void kernel_launch(void* const* d_in, const int* in_sizes, int n_in,
                              void* d_out, int out_size, void* d_ws, size_t ws_size,
                              hipStream_t stream) {
    const float* mapx = (const float*)d_in[0];
    const float* agt  = (const float*)d_in[1];
    const int*   u    = (const int*)d_in[2];
    const int*   v    = (const int*)d_in[3];
    const float* W0   = (const float*)d_in[4];
    const float* b0   = (const float*)d_in[5];
    const float* W1   = (const float*)d_in[6];
    const float* g1   = (const float*)d_in[7];
    const float* b1   = (const float*)d_in[8];
    const float* Wa   = (const float*)d_in[9];
    const float* g_bn = (const float*)d_in[10];
    const float* b_bn = (const float*)d_in[11];
    const float* Wf   = (const float*)d_in[12];
    const float* g_fc = (const float*)d_in[13];
    const float* b_fc = (const float*)d_in[14];
    int N = in_sizes[0] / 8;      // 500000
    int A = in_sizes[1] / 80;     // 20000
    int E = in_sizes[2];          // 500000
    float* out = (float*)d_out;

    char* ws = (char*)d_ws;
    unsigned short* Pb  = (unsigned short*)(ws + 0);
    float*    WaT       = (float*)(ws + 5120000);
    ushort_t* W1b       = (ushort_t*)(ws + 5160960);
    ushort_t* Wfb       = (ushort_t*)(ws + 5193728);
    int*      cnt       = (int*)(ws + 5259264);
    int*      cursor    = (int*)(ws + 7259264);
    int*      rp        = (int*)(ws + 9259264);
    int*      partials  = (int*)(ws + 11259392);
    int*      colv      = (int*)(ws + 11261440);

    const int nb_scan = (N + 4095) / 4096;           // 123
    const int nb_e = (E + 255) / 256;

    prep<<<232, 256, 0, stream>>>(W1, Wf, Wa, W1b, Wfb, WaT);
    hipMemsetAsync(cnt, 0, 4000000, stream);          // cnt + cursor
    hist_v<<<nb_e, 256, 0, stream>>>(v, cnt, E);
    proj_agents<<<A / 32, 256, 0, stream>>>(agt, WaT, Pb);
    scan1<<<nb_scan, 256, 0, stream>>>(cnt, rp, partials, N);
    scan2<<<1, 256, 0, stream>>>(partials, nb_scan);
    scan3<<<(N + 255) / 256, 256, 0, stream>>>(rp, partials, N, E);
    fill_csr<<<nb_e, 256, 0, stream>>>(u, v, rp, cursor, colv, E);

    int ntiles = N / 32;          // 15625 exact
    fused<<<1024, 256, 0, stream>>>(mapx, W0, b0, W1b, g1, b1, Pb, rp, colv,
                                    g_bn, b_bn, Wfb, g_fc, b_fc, out, ntiles);
}

// Round 5
// 470.045 us; speedup vs baseline: 1.0190x; 1.0190x over previous
//
#include <hip/hip_runtime.h>
#include <stdint.h>

#define EPS 1e-5f

typedef short bh8 __attribute__((ext_vector_type(8)));   // 8 bf16 in 4 VGPRs
typedef float f4v __attribute__((ext_vector_type(4)));   // MFMA accumulator
typedef unsigned short ushort_t;

static __device__ __forceinline__ unsigned short f2bf(float f) {
    unsigned u = __builtin_bit_cast(unsigned, f);
    u += 0x7fffu + ((u >> 16) & 1u);          // RNE
    return (unsigned short)(u >> 16);
}

static __device__ __forceinline__ float bfbits(unsigned x) {
    return __builtin_bit_cast(float, x);
}

// accumulate 16 bf16 channels (2×uint4) into tv
static __device__ __forceinline__ void acc16(float* tv, uint4 qa, uint4 qb) {
    unsigned wd[8] = {qa.x, qa.y, qa.z, qa.w, qb.x, qb.y, qb.z, qb.w};
#pragma unroll
    for (int p = 0; p < 8; ++p) {
        tv[2 * p + 0] += bfbits(wd[p] << 16);
        tv[2 * p + 1] += bfbits(wd[p] & 0xffff0000u);
    }
}

struct EdgeBufs { uint4 a0, b0, a1, b1, a2, b2, a3, b3; };

// exec-masked issue of up to 4 edge rows (16 channels each at pB)
static __device__ __forceinline__ EdgeBufs gather_issue(const unsigned short* pB,
                                                        int deg, int ca, int cb,
                                                        int cc, int cd) {
    EdgeBufs e;
    uint4 z = {0, 0, 0, 0};
    e.a0 = z; e.b0 = z; e.a1 = z; e.b1 = z;
    e.a2 = z; e.b2 = z; e.a3 = z; e.b3 = z;
    if (deg > 0) { const uint4* p = (const uint4*)(pB + (size_t)ca * 128); e.a0 = p[0]; e.b0 = p[1]; }
    if (deg > 1) { const uint4* p = (const uint4*)(pB + (size_t)cb * 128); e.a1 = p[0]; e.b1 = p[1]; }
    if (deg > 2) { const uint4* p = (const uint4*)(pB + (size_t)cc * 128); e.a2 = p[0]; e.b2 = p[1]; }
    if (deg > 3) { const uint4* p = (const uint4*)(pB + (size_t)cd * 128); e.a3 = p[0]; e.b3 = p[1]; }
    return e;
}

static __device__ __forceinline__ void acc_edges(float* tv, const EdgeBufs& e) {
    acc16(tv, e.a0, e.b0);
    acc16(tv, e.a1, e.b1);
    acc16(tv, e.a2, e.b2);
    acc16(tv, e.a3, e.b3);
}

// rare tail: deg>4 (P≈0.4% per row)
static __device__ __forceinline__ void gather_tail(float* tv, const unsigned short* pB,
                                                   const int* col, int beg, int deg) {
    for (int k = 4; k < deg; ++k) {
        const int a = col[beg + k];
        const uint4* p = (const uint4*)(pB + (size_t)a * 128);
        uint4 qa = p[0], qb = p[1];
        acc16(tv, qa, qb);
    }
}

// h0 = relu(mapx@W0^T + b0) row -> bf16 swizzled LDS
static __device__ __forceinline__ void h0_compute(const float* mx, short* dst,
                                                  const float* W0s, const float* b0s,
                                                  int rA, int cg) {
    __align__(16) unsigned short hb[16];
#pragma unroll
    for (int c = 0; c < 16; ++c) {
        const int cc = 16 * cg + c;
        float a = b0s[cc];
#pragma unroll
        for (int j = 0; j < 8; ++j) a = fmaf(mx[j], W0s[cc * 8 + j], a);
        hb[c] = f2bf(fmaxf(a, 0.f));
    }
    const int base = rA * 256 + cg * 32;
#pragma unroll
    for (int pc = 0; pc < 2; ++pc) {
        const int a = (base + 16 * pc) ^ ((rA & 7) << 4);
        *(uint4*)((char*)dst + a) = *(const uint4*)&hb[8 * pc];
    }
}

// ---------------- ws layout (bytes) ----------------
// Pb   (bf16): 0          size 5,120,000
// WaT  (f32) : 5,120,000  size 40,960
// W1b  (bf16): 5,160,960  size 32,768
// Wfb  (bf16): 5,193,728  size 65,536
// cnt  (int) : 5,259,264  size 2,000,000
// cursor(int): 7,259,264  size 2,000,000
// rp   (int) : 9,259,264  size 2,000,004
// partials   : 11,259,392 size 492
// col  (int) : 11,261,440 size 2,000,000

__global__ void prep(const float* __restrict__ W1, const float* __restrict__ Wf,
                     const float* __restrict__ Wa, ushort_t* __restrict__ W1b,
                     ushort_t* __restrict__ Wfb, float* __restrict__ WaT) {
    int i = blockIdx.x * 256 + threadIdx.x;
    if (i < 16384) W1b[i] = f2bf(W1[i]);
    else if (i < 49152) { int j = i - 16384; Wfb[j] = f2bf(Wf[j]); }
    else if (i < 59392) { int l2 = i - 49152; int k = l2 >> 7, c = l2 & 127; WaT[l2] = Wa[c * 80 + k]; }
}

__global__ __launch_bounds__(256) void proj_agents(const float* __restrict__ agt,
                                                   const float* __restrict__ WaT,
                                                   unsigned short* __restrict__ Pb) {
    __shared__ float WT[80 * 128];
    __shared__ float xT[80][32];
    int t = threadIdx.x;
    int row0 = blockIdx.x * 32;
#pragma unroll
    for (int m = 0; m < 40; ++m) WT[t + 256 * m] = WaT[t + 256 * m];
#pragma unroll
    for (int m = 0; m < 10; ++m) {
        int f = t + 256 * m;
        int r = f / 80, k = f - r * 80;
        xT[k][r] = agt[(size_t)(row0 + r) * 80 + k];
    }
    __syncthreads();
    int tx = t & 31, ty = t >> 5;
    float acc[4][4] = {};
    for (int k = 0; k < 80; ++k) {
        float4 xv = *(const float4*)&xT[k][ty * 4];
        float4 wv = *(const float4*)&WT[k * 128 + tx * 4];
        float xa[4] = {xv.x, xv.y, xv.z, xv.w};
        float wa[4] = {wv.x, wv.y, wv.z, wv.w};
#pragma unroll
        for (int i = 0; i < 4; ++i)
#pragma unroll
            for (int j = 0; j < 4; ++j) acc[i][j] = fmaf(xa[i], wa[j], acc[i][j]);
    }
#pragma unroll
    for (int i = 0; i < 4; ++i) {
        int r = row0 + ty * 4 + i;
        union { unsigned short s[4]; uint2 q; } o;
#pragma unroll
        for (int j = 0; j < 4; ++j) o.s[j] = f2bf(acc[i][j]);
        *(uint2*)&Pb[(size_t)r * 128 + tx * 4] = o.q;
    }
}

__global__ void hist_v(const int* __restrict__ v, int* __restrict__ cnt, int E) {
    int e = blockIdx.x * 256 + threadIdx.x;
    if (e < E) atomicAdd(&cnt[v[e]], 1);
}

__global__ __launch_bounds__(256) void scan1(const int* __restrict__ cnt,
                                             int* __restrict__ rp,
                                             int* __restrict__ partials, int n) {
    __shared__ int lds[256];
    int b = blockIdx.x, t = threadIdx.x;
    int base = b * 4096 + t * 16;
    int vv[16];
    int run = 0;
#pragma unroll
    for (int i = 0; i < 16; ++i) {
        int c = (base + i < n) ? cnt[base + i] : 0;
        vv[i] = run;
        run += c;
    }
    lds[t] = run;
    __syncthreads();
#pragma unroll
    for (int off = 1; off < 256; off <<= 1) {
        int x = (t >= off) ? lds[t - off] : 0;
        __syncthreads();
        lds[t] += x;
        __syncthreads();
    }
    int excl = lds[t] - run;
    if (t == 255) partials[b] = lds[255];
#pragma unroll
    for (int i = 0; i < 16; ++i)
        if (base + i < n) rp[base + i] = excl + vv[i];
}

__global__ __launch_bounds__(256) void scan2(int* __restrict__ partials, int nb) {
    __shared__ int lds[256];
    int t = threadIdx.x;
    int vv = (t < nb) ? partials[t] : 0;
    lds[t] = vv;
    __syncthreads();
#pragma unroll
    for (int off = 1; off < 256; off <<= 1) {
        int x = (t >= off) ? lds[t - off] : 0;
        __syncthreads();
        lds[t] += x;
        __syncthreads();
    }
    if (t < nb) partials[t] = lds[t] - vv;
}

__global__ void scan3(int* __restrict__ rp, const int* __restrict__ partials,
                      int n, int E) {
    int i = blockIdx.x * 256 + threadIdx.x;
    if (i < n) rp[i] += partials[i >> 12];
    if (i == 0) rp[n] = E;
}

__global__ void fill_csr(const int* __restrict__ u, const int* __restrict__ v,
                         const int* __restrict__ rp, int* __restrict__ cursor,
                         int* __restrict__ col, int E) {
    int e = blockIdx.x * 256 + threadIdx.x;
    if (e < E) {
        int vv = v[e];
        int pos = rp[vv] + atomicAdd(&cursor[vv], 1);
        col[pos] = u[e];
    }
}

// ---------------- fused kernel: 3 barriers/tile, depth-3 prefetch pipeline ----------------
// 32 rows/tile, 4 waves; wave w owns output cols [32w,32w+32).
// All global loads for t+1..t+3 issue at the TOP of the long phase (GEMM3 + h0-next +
// GN-fc ≈ 800cy) so the barrier drain (vmcnt(0) at every __syncthreads) costs ~0.
__global__ __launch_bounds__(256, 3) void fused(
    const float* __restrict__ mapx, const float* __restrict__ W0,
    const float* __restrict__ b0, const ushort_t* __restrict__ W1b,
    const float* __restrict__ g1, const float* __restrict__ b1,
    const unsigned short* __restrict__ Pb, const int* __restrict__ rp,
    const int* __restrict__ col, const float* __restrict__ g_bn,
    const float* __restrict__ b_bn, const ushort_t* __restrict__ Wfb,
    const float* __restrict__ g_fc, const float* __restrict__ b_fc,
    float* __restrict__ out, int ntiles)
{
    __shared__ __align__(16) short h0s[2][32 * 128];   // 2×8 KB, XOR-swizzled
    __shared__ __align__(16) short cats[32 * 256];     // 16 KB, XOR-swizzled
    __shared__ float W0s[128 * 8];
    __shared__ float b0s[128];
    __shared__ float2 partA[4][32], partC[4][32];
    __shared__ float gA[128], bA[128], gB[128], bB[128], gC[128], bC[128];

    const int t = threadIdx.x;
    const int w = t >> 6;
    const int l = t & 63;
    const int l15 = l & 15, lg = l >> 4;
    const int r2 = t >> 3, c0 = (t & 7) * 16;          // gather mapping
    const int rA = t & 31, cg = t >> 5;                // h0 mapping

    if (t < 128) {
        gA[t] = g1[t];   bA[t] = b1[t];
        gB[t] = g_bn[t]; bB[t] = b_bn[t];
        gC[t] = g_fc[t]; bC[t] = b_fc[t];
        b0s[t] = b0[t];
    }
    for (int i = t; i < 1024; i += 256) W0s[i] = W0[i];

    bh8 w1b[2][4], wfb[2][8];
#pragma unroll
    for (int n = 0; n < 2; ++n) {
        const int wr = 32 * w + 16 * n + l15;          // weight row = output col
#pragma unroll
        for (int s = 0; s < 4; ++s)
            w1b[n][s] = *(const bh8*)(W1b + (size_t)wr * 128 + s * 32 + lg * 8);
#pragma unroll
        for (int s = 0; s < 8; ++s)
            wfb[n][s] = *(const bh8*)(Wfb + (size_t)wr * 256 + s * 32 + lg * 8);
    }
    __syncthreads();

    const f4v fzero = {0.f, 0.f, 0.f, 0.f};
    const int stride = (int)gridDim.x;
    const int tile0 = blockIdx.x;
    const unsigned short* pB = Pb + c0;

    // ---- pipeline registers ----
    int beg1, deg1, beg2, deg2;            // rp for t+1, t+2
    int c1a, c1b, c1c, c1d;                // col4 for t+1
    float mx1[8];                          // mapx row for t+1
    float tv[16];                          // messages for current tile

    { // ---- prologue: prime tiles t0, t0+s, t0+2s ----
        int tB = tile0 + stride;     if (tB >= ntiles) tB = 0;
        int tC = tile0 + 2 * stride; if (tC >= ntiles) tC = 0;
        int beg0, deg0;
        { int rr = tile0 * 32 + r2; beg0 = rp[rr]; deg0 = rp[rr + 1] - beg0; }
        { int rr = tB * 32 + r2;    beg1 = rp[rr]; deg1 = rp[rr + 1] - beg1; }
        { int rr = tC * 32 + r2;    beg2 = rp[rr]; deg2 = rp[rr + 1] - beg2; }
        int c0a = col[(deg0 > 0) ? beg0 : 0], c0b = col[(deg0 > 1) ? beg0 + 1 : 0];
        int c0c = col[(deg0 > 2) ? beg0 + 2 : 0], c0d = col[(deg0 > 3) ? beg0 + 3 : 0];
        c1a = col[(deg1 > 0) ? beg1 : 0]; c1b = col[(deg1 > 1) ? beg1 + 1 : 0];
        c1c = col[(deg1 > 2) ? beg1 + 2 : 0]; c1d = col[(deg1 > 3) ? beg1 + 3 : 0];
        float mx0[8];
        { const float* p = mapx + (size_t)(tile0 * 32 + rA) * 8;
          *(float4*)&mx0[0] = *(const float4*)p; *(float4*)&mx0[4] = *(const float4*)(p + 4); }
        { const float* p = mapx + (size_t)(tB * 32 + rA) * 8;
          *(float4*)&mx1[0] = *(const float4*)p; *(float4*)&mx1[4] = *(const float4*)(p + 4); }
        EdgeBufs eb = gather_issue(pB, deg0, c0a, c0b, c0c, c0d);
        h0_compute(mx0, h0s[0], W0s, b0s, rA, cg);
#pragma unroll
        for (int i = 0; i < 16; ++i) tv[i] = 0.f;
        acc_edges(tv, eb);
        gather_tail(tv, pB, col, beg0, deg0);
        __syncthreads();                               // h0s[0] ready
    }
    int cur = 0;

    for (int tile = tile0; tile < ntiles; tile += stride) {
        const int row0 = tile * 32;

        // ===== STEP2: GEMM2 from h0s[cur] =====
        f4v acc2[2][2];
#pragma unroll
        for (int m = 0; m < 2; ++m)
#pragma unroll
            for (int n = 0; n < 2; ++n) acc2[m][n] = fzero;
        const short* h0cur = h0s[cur];
#pragma unroll
        for (int s = 0; s < 4; ++s) {
            bh8 af[2];
#pragma unroll
            for (int m = 0; m < 2; ++m) {
                const int row = 16 * m + l15;
                const int a = (row * 256 + s * 64 + lg * 16) ^ ((row & 7) << 4);
                af[m] = *(const bh8*)((const char*)h0cur + a);
            }
#pragma unroll
            for (int m = 0; m < 2; ++m)
#pragma unroll
                for (int n = 0; n < 2; ++n)
                    acc2[m][n] = __builtin_amdgcn_mfma_f32_16x16x32_bf16(
                        w1b[n][s], af[m], acc2[m][n], 0, 0, 0);
        }

        // GN1 partials
#pragma unroll
        for (int m = 0; m < 2; ++m) {
            float a = 0.f, q = 0.f;
#pragma unroll
            for (int n = 0; n < 2; ++n)
#pragma unroll
                for (int reg = 0; reg < 4; ++reg) {
                    float x = acc2[m][n][reg];
                    a += x; q += x * x;
                }
            a += __shfl_xor(a, 16, 64); q += __shfl_xor(q, 16, 64);
            a += __shfl_xor(a, 32, 64); q += __shfl_xor(q, 32, 64);
            if (lg == 0) partA[w][16 * m + l15] = make_float2(a, q);
        }
        __syncthreads();                               // barA

        // ===== STEP4: stats, cats writes =====
        float meanA[2], invA[2];
#pragma unroll
        for (int m = 0; m < 2; ++m) {
            const int row = 16 * m + l15;
            float2 p0 = partA[0][row], p1 = partA[1][row];
            float2 p2 = partA[2][row], p3 = partA[3][row];
            float a = p0.x + p1.x + p2.x + p3.x;
            float q = p0.y + p1.y + p2.y + p3.y;
            float mean = a * (1.f / 128.f);
            float var = q * (1.f / 128.f) - mean * mean;
            meanA[m] = mean;
            invA[m] = rsqrtf(var + EPS);
        }
#pragma unroll
        for (int m = 0; m < 2; ++m) {
            const int row = 16 * m + l15;
#pragma unroll
            for (int n = 0; n < 2; ++n) {
                const int c00 = 32 * w + 16 * n + 4 * lg;
                union { unsigned short s[4]; uint2 q; } o;
#pragma unroll
                for (int reg = 0; reg < 4; ++reg) {
                    float v2 = (acc2[m][n][reg] - meanA[m]) * invA[m] * gA[c00 + reg] + bA[c00 + reg];
                    o.s[reg] = f2bf(fmaxf(v2, 0.f));
                }
                const int a = (row * 512 + c00 * 2) ^ ((row & 7) << 4);
                *(uint2*)((char*)cats + a) = o.q;
            }
        }
        {   // message GN from tv (computed last tile) -> cats[:,128:256]
            float a = 0.f, q = 0.f;
#pragma unroll
            for (int i = 0; i < 16; ++i) { a += tv[i]; q += tv[i] * tv[i]; }
#pragma unroll
            for (int msk = 1; msk < 8; msk <<= 1) {
                a += __shfl_xor(a, msk, 64);
                q += __shfl_xor(q, msk, 64);
            }
            const float mean = a * (1.f / 128.f);
            const float var = q * (1.f / 128.f) - mean * mean;
            const float inv = rsqrtf(var + EPS);
            __align__(16) unsigned short tb[16];
#pragma unroll
            for (int i = 0; i < 16; ++i) {
                const int cc = c0 + i;
                tb[i] = f2bf(fmaxf((tv[i] - mean) * inv * gB[cc] + bB[cc], 0.f));
            }
            const int base = r2 * 512 + 256 + c0 * 2;
#pragma unroll
            for (int pc = 0; pc < 2; ++pc) {
                const int ad = (base + 16 * pc) ^ ((r2 & 7) << 4);
                *(uint4*)((char*)cats + ad) = *(const uint4*)&tb[8 * pc];
            }
        }
        __syncthreads();                               // barB

        // ===== STEP5: prefetch issues FIRST, then GEMM3 + h0-next + gather-acc =====
        int tl2 = tile + 2 * stride; if (tl2 >= ntiles) tl2 = 0;
        int tl3 = tile + 3 * stride; if (tl3 >= ntiles) tl3 = 0;
        int beg3, deg3;
        { int rr = tl3 * 32 + r2; beg3 = rp[rr]; deg3 = rp[rr + 1] - beg3; }
        int c2a = col[(deg2 > 0) ? beg2 : 0], c2b = col[(deg2 > 1) ? beg2 + 1 : 0];
        int c2c = col[(deg2 > 2) ? beg2 + 2 : 0], c2d = col[(deg2 > 3) ? beg2 + 3 : 0];
        float mx2[8];
        { const float* p = mapx + (size_t)(tl2 * 32 + rA) * 8;
          *(float4*)&mx2[0] = *(const float4*)p; *(float4*)&mx2[4] = *(const float4*)(p + 4); }
        EdgeBufs eb = gather_issue(pB, deg1, c1a, c1b, c1c, c1d);

        f4v acc3[2][2];
#pragma unroll
        for (int m = 0; m < 2; ++m)
#pragma unroll
            for (int n = 0; n < 2; ++n) acc3[m][n] = fzero;
#pragma unroll
        for (int s = 0; s < 8; ++s) {
            bh8 af[2];
#pragma unroll
            for (int m = 0; m < 2; ++m) {
                const int row = 16 * m + l15;
                const int a = (row * 512 + s * 64 + lg * 16) ^ ((row & 7) << 4);
                af[m] = *(const bh8*)((const char*)cats + a);
            }
#pragma unroll
            for (int m = 0; m < 2; ++m)
#pragma unroll
                for (int n = 0; n < 2; ++n)
                    acc3[m][n] = __builtin_amdgcn_mfma_f32_16x16x32_bf16(
                        wfb[n][s], af[m], acc3[m][n], 0, 0, 0);
        }

        // next-tile h0 into the other buffer (hides Pb/mapx latency under VALU)
        h0_compute(mx1, h0s[cur ^ 1], W0s, b0s, rA, cg);

        // accumulate next tile's messages
        float tvN[16] = {};
        acc_edges(tvN, eb);
        gather_tail(tvN, pB, col, beg1, deg1);

        // GN-fc partials
#pragma unroll
        for (int m = 0; m < 2; ++m) {
            float a = 0.f, q = 0.f;
#pragma unroll
            for (int n = 0; n < 2; ++n)
#pragma unroll
                for (int reg = 0; reg < 4; ++reg) {
                    float x = acc3[m][n][reg];
                    a += x; q += x * x;
                }
            a += __shfl_xor(a, 16, 64); q += __shfl_xor(q, 16, 64);
            a += __shfl_xor(a, 32, 64); q += __shfl_xor(q, 32, 64);
            if (lg == 0) partC[w][16 * m + l15] = make_float2(a, q);
        }
        __syncthreads();                               // barC (drains step-5 loads, mostly done)

        // ===== STEP7: epilogue =====
#pragma unroll
        for (int m = 0; m < 2; ++m) {
            const int row = 16 * m + l15;
            float2 p0 = partC[0][row], p1 = partC[1][row];
            float2 p2 = partC[2][row], p3 = partC[3][row];
            float a = p0.x + p1.x + p2.x + p3.x;
            float q = p0.y + p1.y + p2.y + p3.y;
            float mean = a * (1.f / 128.f);
            float var = q * (1.f / 128.f) - mean * mean;
            float inv = rsqrtf(var + EPS);
#pragma unroll
            for (int n = 0; n < 2; ++n) {
                const int c00 = 32 * w + 16 * n + 4 * lg;
                float4 o;
                o.x = fmaxf((acc3[m][n][0] - mean) * inv * gC[c00 + 0] + bC[c00 + 0], 0.f);
                o.y = fmaxf((acc3[m][n][1] - mean) * inv * gC[c00 + 1] + bC[c00 + 1], 0.f);
                o.z = fmaxf((acc3[m][n][2] - mean) * inv * gC[c00 + 2] + bC[c00 + 2], 0.f);
                o.w = fmaxf((acc3[m][n][3] - mean) * inv * gC[c00 + 3] + bC[c00 + 3], 0.f);
                *(float4*)&out[(size_t)(row0 + row) * 128 + c00] = o;
            }
        }

        // rotate pipeline state
        beg1 = beg2; deg1 = deg2; beg2 = beg3; deg2 = deg3;
        c1a = c2a; c1b = c2b; c1c = c2c; c1d = c2d;
#pragma unroll
        for (int i = 0; i < 8; ++i) mx1[i] = mx2[i];
#pragma unroll
        for (int i = 0; i < 16; ++i) tv[i] = tvN[i];
        cur ^= 1;
    }
}

extern "C" void kernel_launch(void* const* d_in, const int* in_sizes, int n_in,
                              void* d_out, int out_size, void* d_ws, size_t ws_size,
                              hipStream_t stream) {
    const float* mapx = (const float*)d_in[0];
    const float* agt  = (const float*)d_in[1];
    const int*   u    = (const int*)d_in[2];
    const int*   v    = (const int*)d_in[3];
    const float* W0   = (const float*)d_in[4];
    const float* b0   = (const float*)d_in[5];
    const float* W1   = (const float*)d_in[6];
    const float* g1   = (const float*)d_in[7];
    const float* b1   = (const float*)d_in[8];
    const float* Wa   = (const float*)d_in[9];
    const float* g_bn = (const float*)d_in[10];
    const float* b_bn = (const float*)d_in[11];
    const float* Wf   = (const float*)d_in[12];
    const float* g_fc = (const float*)d_in[13];
    const float* b_fc = (const float*)d_in[14];
    int N = in_sizes[0] / 8;      // 500000
    int A = in_sizes[1] / 80;     // 20000
    int E = in_sizes[2];          // 500000
    float* out = (float*)d_out;

    char* ws = (char*)d_ws;
    unsigned short* Pb  = (unsigned short*)(ws + 0);
    float*    WaT       = (float*)(ws + 5120000);
    ushort_t* W1b       = (ushort_t*)(ws + 5160960);
    ushort_t* Wfb       = (ushort_t*)(ws + 5193728);
    int*      cnt       = (int*)(ws + 5259264);
    int*      cursor    = (int*)(ws + 7259264);
    int*      rp        = (int*)(ws + 9259264);
    int*      partials  = (int*)(ws + 11259392);
    int*      colv      = (int*)(ws + 11261440);

    const int nb_scan = (N + 4095) / 4096;           // 123
    const int nb_e = (E + 255) / 256;

    prep<<<232, 256, 0, stream>>>(W1, Wf, Wa, W1b, Wfb, WaT);
    hipMemsetAsync(cnt, 0, 4000000, stream);          // cnt + cursor
    hist_v<<<nb_e, 256, 0, stream>>>(v, cnt, E);
    proj_agents<<<A / 32, 256, 0, stream>>>(agt, WaT, Pb);
    scan1<<<nb_scan, 256, 0, stream>>>(cnt, rp, partials, N);
    scan2<<<1, 256, 0, stream>>>(partials, nb_scan);
    scan3<<<(N + 255) / 256, 256, 0, stream>>>(rp, partials, N, E);
    fill_csr<<<nb_e, 256, 0, stream>>>(u, v, rp, cursor, colv, E);

    int ntiles = N / 32;          // 15625 exact
    fused<<<768, 256, 0, stream>>>(mapx, W0, b0, W1b, g1, b1, Pb, rp, colv,
                                   g_bn, b_bn, Wfb, g_fc, b_fc, out, ntiles);
}

// Round 6
// 384.985 us; speedup vs baseline: 1.2442x; 1.2209x over previous
//
#include <hip/hip_runtime.h>
#include <stdint.h>

#define EPS 1e-5f

typedef short bh8 __attribute__((ext_vector_type(8)));   // 8 bf16 in 4 VGPRs
typedef float f4v __attribute__((ext_vector_type(4)));   // MFMA accumulator
typedef unsigned short ushort_t;

static __device__ __forceinline__ unsigned short f2bf(float f) {
    unsigned u = __builtin_bit_cast(unsigned, f);
    u += 0x7fffu + ((u >> 16) & 1u);          // RNE
    return (unsigned short)(u >> 16);
}

static __device__ __forceinline__ float bfbits(unsigned x) {
    return __builtin_bit_cast(float, x);
}

// accumulate 16 bf16 channels (2×uint4) into tv
static __device__ __forceinline__ void acc16(float* tv, uint4 qa, uint4 qb) {
    unsigned wd[8] = {qa.x, qa.y, qa.z, qa.w, qb.x, qb.y, qb.z, qb.w};
#pragma unroll
    for (int p = 0; p < 8; ++p) {
        tv[2 * p + 0] += bfbits(wd[p] << 16);
        tv[2 * p + 1] += bfbits(wd[p] & 0xffff0000u);
    }
}

// ---------------- ws layout (bytes) ----------------
// Pb   (bf16): 0          size 5,120,000
// WaT  (f32) : 5,120,000  size 40,960
// W1b  (bf16): 5,160,960  size 32,768
// Wfb  (bf16): 5,193,728  size 65,536
// cnt  (int) : 5,259,264  size 2,000,000
// cursor(int): 7,259,264  size 2,000,000
// rp   (int) : 9,259,264  size 2,000,004
// partials   : 11,259,392 size 492
// col  (int) : 11,261,440 size 2,000,000
// catB (bf16): 16,777,216 size 128,000,000

__global__ void prep(const float* __restrict__ W1, const float* __restrict__ Wf,
                     const float* __restrict__ Wa, ushort_t* __restrict__ W1b,
                     ushort_t* __restrict__ Wfb, float* __restrict__ WaT) {
    int i = blockIdx.x * 256 + threadIdx.x;
    if (i < 16384) W1b[i] = f2bf(W1[i]);
    else if (i < 49152) { int j = i - 16384; Wfb[j] = f2bf(Wf[j]); }
    else if (i < 59392) { int l2 = i - 49152; int k = l2 >> 7, c = l2 & 127; WaT[l2] = Wa[c * 80 + k]; }
}

__global__ __launch_bounds__(256) void proj_agents(const float* __restrict__ agt,
                                                   const float* __restrict__ WaT,
                                                   unsigned short* __restrict__ Pb) {
    __shared__ float WT[80 * 128];
    __shared__ float xT[80][32];
    int t = threadIdx.x;
    int row0 = blockIdx.x * 32;
#pragma unroll
    for (int m = 0; m < 40; ++m) WT[t + 256 * m] = WaT[t + 256 * m];
#pragma unroll
    for (int m = 0; m < 10; ++m) {
        int f = t + 256 * m;
        int r = f / 80, k = f - r * 80;
        xT[k][r] = agt[(size_t)(row0 + r) * 80 + k];
    }
    __syncthreads();
    int tx = t & 31, ty = t >> 5;
    float acc[4][4] = {};
    for (int k = 0; k < 80; ++k) {
        float4 xv = *(const float4*)&xT[k][ty * 4];
        float4 wv = *(const float4*)&WT[k * 128 + tx * 4];
        float xa[4] = {xv.x, xv.y, xv.z, xv.w};
        float wa[4] = {wv.x, wv.y, wv.z, wv.w};
#pragma unroll
        for (int i = 0; i < 4; ++i)
#pragma unroll
            for (int j = 0; j < 4; ++j) acc[i][j] = fmaf(xa[i], wa[j], acc[i][j]);
    }
#pragma unroll
    for (int i = 0; i < 4; ++i) {
        int r = row0 + ty * 4 + i;
        union { unsigned short s[4]; uint2 q; } o;
#pragma unroll
        for (int j = 0; j < 4; ++j) o.s[j] = f2bf(acc[i][j]);
        *(uint2*)&Pb[(size_t)r * 128 + tx * 4] = o.q;
    }
}

__global__ void hist_v(const int* __restrict__ v, int* __restrict__ cnt, int E) {
    int e = blockIdx.x * 256 + threadIdx.x;
    if (e < E) atomicAdd(&cnt[v[e]], 1);
}

__global__ __launch_bounds__(256) void scan1(const int* __restrict__ cnt,
                                             int* __restrict__ rp,
                                             int* __restrict__ partials, int n) {
    __shared__ int lds[256];
    int b = blockIdx.x, t = threadIdx.x;
    int base = b * 4096 + t * 16;
    int vv[16];
    int run = 0;
#pragma unroll
    for (int i = 0; i < 16; ++i) {
        int c = (base + i < n) ? cnt[base + i] : 0;
        vv[i] = run;
        run += c;
    }
    lds[t] = run;
    __syncthreads();
#pragma unroll
    for (int off = 1; off < 256; off <<= 1) {
        int x = (t >= off) ? lds[t - off] : 0;
        __syncthreads();
        lds[t] += x;
        __syncthreads();
    }
    int excl = lds[t] - run;
    if (t == 255) partials[b] = lds[255];
#pragma unroll
    for (int i = 0; i < 16; ++i)
        if (base + i < n) rp[base + i] = excl + vv[i];
}

__global__ __launch_bounds__(256) void scan2(int* __restrict__ partials, int nb) {
    __shared__ int lds[256];
    int t = threadIdx.x;
    int vv = (t < nb) ? partials[t] : 0;
    lds[t] = vv;
    __syncthreads();
#pragma unroll
    for (int off = 1; off < 256; off <<= 1) {
        int x = (t >= off) ? lds[t - off] : 0;
        __syncthreads();
        lds[t] += x;
        __syncthreads();
    }
    if (t < nb) partials[t] = lds[t] - vv;
}

__global__ void scan3(int* __restrict__ rp, const int* __restrict__ partials,
                      int n, int E) {
    int i = blockIdx.x * 256 + threadIdx.x;
    if (i < n) rp[i] += partials[i >> 12];
    if (i == 0) rp[n] = E;
}

__global__ void fill_csr(const int* __restrict__ u, const int* __restrict__ v,
                         const int* __restrict__ rp, int* __restrict__ cursor,
                         int* __restrict__ col, int E) {
    int e = blockIdx.x * 256 + threadIdx.x;
    if (e < E) {
        int vv = v[e];
        int pos = rp[vv] + atomicAdd(&cursor[vv], 1);
        col[pos] = u[e];
    }
}

// ---------------- gather + GN_bn + ReLU + bf16 pack -> catB[N][128] ----------------
// 8 threads/node, 16 ch each. Isolated kernel: pointer-chase hides under TLP,
// Pb (5 MB) stays L2/L3-hot without the out-stream thrashing it.
__global__ __launch_bounds__(256) void gather_gn(
    const unsigned short* __restrict__ Pb, const int* __restrict__ rp,
    const int* __restrict__ col, const float* __restrict__ g_bn,
    const float* __restrict__ b_bn, ushort_t* __restrict__ catB) {
    const int t = threadIdx.x;
    const int node = blockIdx.x * 32 + (t >> 3);
    const int c0 = (t & 7) * 16;
    const int beg = rp[node];
    const int deg = rp[node + 1] - beg;
    const int ca = col[(deg > 0) ? beg : 0];
    const int cb = col[(deg > 1) ? beg + 1 : 0];
    const int cc = col[(deg > 2) ? beg + 2 : 0];
    const int cd = col[(deg > 3) ? beg + 3 : 0];
    const unsigned short* pB = Pb + c0;
    float tv[16] = {};
    if (deg > 0) { const uint4* p = (const uint4*)(pB + (size_t)ca * 128); acc16(tv, p[0], p[1]); }
    if (deg > 1) { const uint4* p = (const uint4*)(pB + (size_t)cb * 128); acc16(tv, p[0], p[1]); }
    if (deg > 2) { const uint4* p = (const uint4*)(pB + (size_t)cc * 128); acc16(tv, p[0], p[1]); }
    if (deg > 3) { const uint4* p = (const uint4*)(pB + (size_t)cd * 128); acc16(tv, p[0], p[1]); }
    for (int k = 4; k < deg; ++k) {
        const uint4* p = (const uint4*)(pB + (size_t)col[beg + k] * 128);
        acc16(tv, p[0], p[1]);
    }
    float a = 0.f, q = 0.f;
#pragma unroll
    for (int i = 0; i < 16; ++i) { a += tv[i]; q += tv[i] * tv[i]; }
#pragma unroll
    for (int msk = 1; msk < 8; msk <<= 1) {
        a += __shfl_xor(a, msk, 64);
        q += __shfl_xor(q, msk, 64);
    }
    const float mean = a * (1.f / 128.f);
    const float var = q * (1.f / 128.f) - mean * mean;
    const float inv = rsqrtf(var + EPS);
    union { unsigned short s[16]; uint4 q4[2]; } o;
#pragma unroll
    for (int i = 0; i < 16; ++i) {
        const int cch = c0 + i;
        o.s[i] = f2bf(fmaxf((tv[i] - mean) * inv * g_bn[cch] + b_bn[cch], 0.f));
    }
    uint4* dst = (uint4*)(catB + (size_t)node * 128 + c0);
    dst[0] = o.q4[0];
    dst[1] = o.q4[1];
}

// ---------------- fused kernel: 512 threads, 8 waves, wave w owns cols [16w,16w+16) ----------------
// Per-wave weight fragments: 48 regs (was 96) -> __launch_bounds__(512,4) targets 16 waves/CU.
// MFMA swapped-operand recipe: acc[m] = mfma(Wfrag, Xfrag[m], acc):
//   D col(lane&15) = data row 16m+l15; D row(4lg+reg) = output col 16w+4lg+reg.
__global__ __launch_bounds__(512, 4) void fused(
    const float* __restrict__ mapx, const float* __restrict__ W0,
    const float* __restrict__ b0, const ushort_t* __restrict__ W1b,
    const float* __restrict__ g1, const float* __restrict__ b1,
    const ushort_t* __restrict__ catB, const ushort_t* __restrict__ Wfb,
    const float* __restrict__ g_fc, const float* __restrict__ b_fc,
    float* __restrict__ out, int ntiles)
{
    __shared__ __align__(16) short h0s[32 * 128];    // 8 KB, XOR-swizzled (^=(row&7)<<4)
    __shared__ __align__(16) short cats[32 * 256];   // 16 KB, XOR-swizzled
    __shared__ float W0s[128 * 8];
    __shared__ float b0s[128];
    __shared__ float2 part[8][32];                   // per-wave GN partials
    __shared__ float gA[128], bA[128], gC[128], bC[128];

    const int t = threadIdx.x;
    const int w = t >> 6;                            // 8 waves
    const int l = t & 63;
    const int l15 = l & 15, lg = l >> 4;

    if (t < 128) {
        gA[t] = g1[t];   bA[t] = b1[t];
        gC[t] = g_fc[t]; bC[t] = b_fc[t];
        b0s[t] = b0[t];
    }
    for (int i = t; i < 1024; i += 512) W0s[i] = W0[i];

    // weight fragments (bf16) in registers: 16 cols/wave
    bh8 w1b[4], wfb[8];
    {
        const int wr = 16 * w + l15;                 // weight row = output col
#pragma unroll
        for (int s = 0; s < 4; ++s)
            w1b[s] = *(const bh8*)(W1b + (size_t)wr * 128 + s * 32 + lg * 8);
#pragma unroll
        for (int s = 0; s < 8; ++s)
            wfb[s] = *(const bh8*)(Wfb + (size_t)wr * 256 + s * 32 + lg * 8);
    }
    __syncthreads();

    const f4v fzero = {0.f, 0.f, 0.f, 0.f};
    const int stride = (int)gridDim.x;

    for (int tile = blockIdx.x; tile < ntiles; tile += stride) {
        const int row0 = tile * 32;

        // ===== phase 0: h0 compute + catB copy into LDS =====
        {   // h0: 16 threads/row, 8 cols each
            const int r = t & 31, cg = t >> 5;       // cg 0..15, cols [8cg,8cg+8)
            float mx[8];
            const float* p = mapx + (size_t)(row0 + r) * 8;
            *(float4*)&mx[0] = *(const float4*)p;
            *(float4*)&mx[4] = *(const float4*)(p + 4);
            __align__(16) unsigned short hb[8];
#pragma unroll
            for (int c = 0; c < 8; ++c) {
                const int cc = 8 * cg + c;
                float a = b0s[cc];
#pragma unroll
                for (int j = 0; j < 8; ++j) a = fmaf(mx[j], W0s[cc * 8 + j], a);
                hb[c] = f2bf(fmaxf(a, 0.f));
            }
            const int a = (r * 256 + cg * 16) ^ ((r & 7) << 4);
            *(uint4*)((char*)h0s + a) = *(const uint4*)&hb[0];
        }
        {   // catB row copy (pre-normalized bf16 messages): 16 threads/row, 16B each
            const int r2 = t >> 4, cb = (t & 15) * 8;    // 8 ch = 16 B
            uint4 q = *(const uint4*)(catB + (size_t)(row0 + r2) * 128 + cb);
            const int ad = (r2 * 512 + 256 + cb * 2) ^ ((r2 & 7) << 4);
            *(uint4*)((char*)cats + ad) = q;
        }
        __syncthreads();                              // (1) h0s ready

        // ===== GEMM2: h1 = h0 @ W1^T (K=128) =====
        f4v acc2[2];
        acc2[0] = fzero; acc2[1] = fzero;
#pragma unroll
        for (int s = 0; s < 4; ++s) {
            bh8 af[2];
#pragma unroll
            for (int m = 0; m < 2; ++m) {
                const int row = 16 * m + l15;
                const int a = (row * 256 + s * 64 + lg * 16) ^ ((row & 7) << 4);
                af[m] = *(const bh8*)((const char*)h0s + a);
            }
#pragma unroll
            for (int m = 0; m < 2; ++m)
                acc2[m] = __builtin_amdgcn_mfma_f32_16x16x32_bf16(
                    w1b[s], af[m], acc2[m], 0, 0, 0);
        }

        // GN1 partials: per m, sum this wave's 16 cols per row
#pragma unroll
        for (int m = 0; m < 2; ++m) {
            float a = acc2[m][0] + acc2[m][1] + acc2[m][2] + acc2[m][3];
            float q = acc2[m][0] * acc2[m][0] + acc2[m][1] * acc2[m][1] +
                      acc2[m][2] * acc2[m][2] + acc2[m][3] * acc2[m][3];
            a += __shfl_xor(a, 16, 64); q += __shfl_xor(q, 16, 64);
            a += __shfl_xor(a, 32, 64); q += __shfl_xor(q, 32, 64);
            if (lg == 0) part[w][16 * m + l15] = make_float2(a, q);
        }
        __syncthreads();                              // (2) part ready

        // stats + normalized h -> cats[:,0:128]
#pragma unroll
        for (int m = 0; m < 2; ++m) {
            const int row = 16 * m + l15;
            float a = 0.f, q = 0.f;
#pragma unroll
            for (int pw = 0; pw < 8; ++pw) {
                float2 pq = part[pw][row];
                a += pq.x; q += pq.y;
            }
            const float mean = a * (1.f / 128.f);
            const float var = q * (1.f / 128.f) - mean * mean;
            const float inv = rsqrtf(var + EPS);
            const int c00 = 16 * w + 4 * lg;
            union { unsigned short s[4]; uint2 q2; } o;
#pragma unroll
            for (int reg = 0; reg < 4; ++reg) {
                float v2 = (acc2[m][reg] - mean) * inv * gA[c00 + reg] + bA[c00 + reg];
                o.s[reg] = f2bf(fmaxf(v2, 0.f));
            }
            const int ad = (row * 512 + c00 * 2) ^ ((row & 7) << 4);
            *(uint2*)((char*)cats + ad) = o.q2;
        }
        __syncthreads();                              // (3) cats ready

        // ===== GEMM3: [h,msg_n] @ Wf^T (K=256) =====
        f4v acc3[2];
        acc3[0] = fzero; acc3[1] = fzero;
#pragma unroll
        for (int s = 0; s < 8; ++s) {
            bh8 af[2];
#pragma unroll
            for (int m = 0; m < 2; ++m) {
                const int row = 16 * m + l15;
                const int a = (row * 512 + s * 64 + lg * 16) ^ ((row & 7) << 4);
                af[m] = *(const bh8*)((const char*)cats + a);
            }
#pragma unroll
            for (int m = 0; m < 2; ++m)
                acc3[m] = __builtin_amdgcn_mfma_f32_16x16x32_bf16(
                    wfb[s], af[m], acc3[m], 0, 0, 0);
        }

        // GN-fc partials
#pragma unroll
        for (int m = 0; m < 2; ++m) {
            float a = acc3[m][0] + acc3[m][1] + acc3[m][2] + acc3[m][3];
            float q = acc3[m][0] * acc3[m][0] + acc3[m][1] * acc3[m][1] +
                      acc3[m][2] * acc3[m][2] + acc3[m][3] * acc3[m][3];
            a += __shfl_xor(a, 16, 64); q += __shfl_xor(q, 16, 64);
            a += __shfl_xor(a, 32, 64); q += __shfl_xor(q, 32, 64);
            if (lg == 0) part[w][16 * m + l15] = make_float2(a, q);
        }
        __syncthreads();                              // (4) part ready

        // epilogue: stats, GN+ReLU, float4 store
#pragma unroll
        for (int m = 0; m < 2; ++m) {
            const int row = 16 * m + l15;
            float a = 0.f, q = 0.f;
#pragma unroll
            for (int pw = 0; pw < 8; ++pw) {
                float2 pq = part[pw][row];
                a += pq.x; q += pq.y;
            }
            const float mean = a * (1.f / 128.f);
            const float var = q * (1.f / 128.f) - mean * mean;
            const float inv = rsqrtf(var + EPS);
            const int c00 = 16 * w + 4 * lg;
            float4 o;
            o.x = fmaxf((acc3[m][0] - mean) * inv * gC[c00 + 0] + bC[c00 + 0], 0.f);
            o.y = fmaxf((acc3[m][1] - mean) * inv * gC[c00 + 1] + bC[c00 + 1], 0.f);
            o.z = fmaxf((acc3[m][2] - mean) * inv * gC[c00 + 2] + bC[c00 + 2], 0.f);
            o.w = fmaxf((acc3[m][3] - mean) * inv * gC[c00 + 3] + bC[c00 + 3], 0.f);
            *(float4*)&out[(size_t)(row0 + row) * 128 + c00] = o;
        }
        __syncthreads();                              // (5) protect h0s/cats for next tile
    }
}

extern "C" void kernel_launch(void* const* d_in, const int* in_sizes, int n_in,
                              void* d_out, int out_size, void* d_ws, size_t ws_size,
                              hipStream_t stream) {
    const float* mapx = (const float*)d_in[0];
    const float* agt  = (const float*)d_in[1];
    const int*   u    = (const int*)d_in[2];
    const int*   v    = (const int*)d_in[3];
    const float* W0   = (const float*)d_in[4];
    const float* b0   = (const float*)d_in[5];
    const float* W1   = (const float*)d_in[6];
    const float* g1   = (const float*)d_in[7];
    const float* b1   = (const float*)d_in[8];
    const float* Wa   = (const float*)d_in[9];
    const float* g_bn = (const float*)d_in[10];
    const float* b_bn = (const float*)d_in[11];
    const float* Wf   = (const float*)d_in[12];
    const float* g_fc = (const float*)d_in[13];
    const float* b_fc = (const float*)d_in[14];
    int N = in_sizes[0] / 8;      // 500000
    int A = in_sizes[1] / 80;     // 20000
    int E = in_sizes[2];          // 500000
    float* out = (float*)d_out;

    char* ws = (char*)d_ws;
    unsigned short* Pb  = (unsigned short*)(ws + 0);
    float*    WaT       = (float*)(ws + 5120000);
    ushort_t* W1b       = (ushort_t*)(ws + 5160960);
    ushort_t* Wfb       = (ushort_t*)(ws + 5193728);
    int*      cnt       = (int*)(ws + 5259264);
    int*      cursor    = (int*)(ws + 7259264);
    int*      rp        = (int*)(ws + 9259264);
    int*      partials  = (int*)(ws + 11259392);
    int*      colv      = (int*)(ws + 11261440);
    ushort_t* catB      = (ushort_t*)(ws + 16777216);

    const int nb_scan = (N + 4095) / 4096;           // 123
    const int nb_e = (E + 255) / 256;

    prep<<<232, 256, 0, stream>>>(W1, Wf, Wa, W1b, Wfb, WaT);
    hipMemsetAsync(cnt, 0, 4000000, stream);          // cnt + cursor
    hist_v<<<nb_e, 256, 0, stream>>>(v, cnt, E);
    proj_agents<<<A / 32, 256, 0, stream>>>(agt, WaT, Pb);
    scan1<<<nb_scan, 256, 0, stream>>>(cnt, rp, partials, N);
    scan2<<<1, 256, 0, stream>>>(partials, nb_scan);
    scan3<<<(N + 255) / 256, 256, 0, stream>>>(rp, partials, N, E);
    fill_csr<<<nb_e, 256, 0, stream>>>(u, v, rp, cursor, colv, E);
    gather_gn<<<N / 32, 256, 0, stream>>>(Pb, rp, colv, g_bn, b_bn, catB);

    int ntiles = N / 32;          // 15625 exact
    fused<<<512, 512, 0, stream>>>(mapx, W0, b0, W1b, g1, b1, catB,
                                   Wfb, g_fc, b_fc, out, ntiles);
}